// Round 8
// baseline (4700.634 us; speedup 1.0000x reference)
//
#include <hip/hip_runtime.h>
#include <math.h>

#define N_NODES 50000
#define E_EDGES 1600000
#define F_IN    128
#define H_DIM   64
#define V_SIZE  16
#define OUT_DIM 2
#define EPS_F   1e-16f

#define NB_SCAN 196   // ceil(50000/256)
#define NBKT    196   // coarse buckets (256 nodes each)
#define EPB     4096  // edges per bin_kernel block

// -------- bf16 helpers --------
__device__ __forceinline__ unsigned bf16r(float x) {
    unsigned u = __float_as_uint(x);
    return (u + 0x7FFFu + ((u >> 16) & 1u)) >> 16;       // RNE
}
__device__ __forceinline__ unsigned bf16pack(float lo, float hi) {
    return bf16r(lo) | (bf16r(hi) << 16);
}
__device__ __forceinline__ float bl(unsigned w) { return __uint_as_float(w << 16); }
__device__ __forceinline__ float bh(unsigned w) { return __uint_as_float(w & 0xFFFF0000u); }

// ---------------- te = edge_emb @ We  (two [16,64] tables) ----------------
__global__ void table_kernel(const float* __restrict__ edge_emb,
                             const float* __restrict__ We1,
                             const float* __restrict__ We2,
                             float* __restrict__ te1, float* __restrict__ te2) {
    int t = blockIdx.x * blockDim.x + threadIdx.x;   // 0..2047
    if (t >= 2 * V_SIZE * H_DIM) return;
    int which = t >> 10;
    int idx = t & 1023;
    int v = idx >> 6, h = idx & 63;
    const float* We = which ? We2 : We1;
    float* te = which ? te2 : te1;
    float acc = 0.f;
    for (int k = 0; k < H_DIM; ++k)
        acc += edge_emb[v * H_DIM + k] * We[k * H_DIM + h];
    te[idx] = acc;
}

// ---------------- CSR build: counting sort of edges by dst ----------------
__global__ void zero_deg_kernel(int* __restrict__ deg) {
    int i = blockIdx.x * blockDim.x + threadIdx.x;
    if (i < N_NODES) deg[i] = 0;
}

__global__ void hist_kernel(const int* __restrict__ ei, int* __restrict__ deg) {
    int e = blockIdx.x * blockDim.x + threadIdx.x;
    if (e >= E_EDGES) return;
    atomicAdd(&deg[ei[E_EDGES + e]], 1);
}

__global__ void scan1_kernel(const int* __restrict__ deg,
                             int* __restrict__ loc, int* __restrict__ bsum) {
    __shared__ int s[256];
    int i = blockIdx.x * 256 + threadIdx.x;
    int v = (i < N_NODES) ? deg[i] : 0;
    s[threadIdx.x] = v;
    __syncthreads();
    for (int off = 1; off < 256; off <<= 1) {
        int t = (threadIdx.x >= off) ? s[threadIdx.x - off] : 0;
        __syncthreads();
        s[threadIdx.x] += t;
        __syncthreads();
    }
    if (i < N_NODES) loc[i] = s[threadIdx.x] - v;   // exclusive
    if (threadIdx.x == 255) bsum[blockIdx.x] = s[255];
}

__global__ void scan2_kernel(const int* __restrict__ bsum, int* __restrict__ bpre) {
    __shared__ int s[256];
    int t = threadIdx.x;
    int v = (t < NB_SCAN) ? bsum[t] : 0;
    s[t] = v;
    __syncthreads();
    for (int off = 1; off < 256; off <<= 1) {
        int u = (t >= off) ? s[t - off] : 0;
        __syncthreads();
        s[t] += u;
        __syncthreads();
    }
    if (t < NB_SCAN) bpre[t] = s[t] - v;            // exclusive
}

__global__ void scan3_kernel(const int* __restrict__ loc, const int* __restrict__ bpre,
                             int* __restrict__ rowptr, int* __restrict__ cursor,
                             int* __restrict__ bcur) {
    int i = blockIdx.x * 256 + threadIdx.x;
    if (i < N_NODES) {
        int r = loc[i] + bpre[blockIdx.x];
        rowptr[i] = r;
        cursor[i] = r;
        if ((i & 255) == 0) bcur[i >> 8] = r;        // coarse-bucket base/cursor
    }
    if (i == 0) rowptr[N_NODES] = E_EDGES;
}

// -------- pass A: bin edges by dst>>8 --------
__global__ __launch_bounds__(256) void bin_kernel(const int* __restrict__ ei,
                                                  const int* __restrict__ attr,
                                                  int* __restrict__ bcur,
                                                  unsigned* __restrict__ ebin) {
    __shared__ unsigned skey[EPB];
    __shared__ unsigned char sbkt[EPB];
    __shared__ int hist[NBKT], base[NBKT];
    const int tid = threadIdx.x;
    for (int i = tid; i < NBKT; i += 256) hist[i] = 0;
    __syncthreads();
    const int e0 = blockIdx.x * EPB;
    for (int i = tid; i < EPB; i += 256) {
        int e = e0 + i;
        if (e < E_EDGES) {
            int src = ei[e], dst = ei[E_EDGES + e], a = attr[e];
            skey[i] = (unsigned)src | ((unsigned)a << 16) | ((unsigned)(dst & 255) << 20);
            int b = dst >> 8;
            sbkt[i] = (unsigned char)b;
            atomicAdd(&hist[b], 1);
        } else {
            sbkt[i] = 0xFF;
        }
    }
    __syncthreads();
    for (int i = tid; i < NBKT; i += 256) {
        int h = hist[i];
        base[i] = h ? atomicAdd(&bcur[i], h) : 0;
        hist[i] = 0;                                  // reuse as rank counter
    }
    __syncthreads();
    for (int i = tid; i < EPB; i += 256) {
        int b = sbkt[i];
        if (b != 0xFF) {
            int r = atomicAdd(&hist[b], 1);
            ebin[base[b] + r] = skey[i];
        }
    }
}

// -------- pass B: exact placement within 32KB bucket windows --------
__global__ __launch_bounds__(256) void place_kernel(const int* __restrict__ rowptr,
                                                    const unsigned* __restrict__ ebin,
                                                    int* __restrict__ cursor,
                                                    unsigned* __restrict__ epack) {
    int b = blockIdx.x;
    int n0 = b << 8;
    int n1 = n0 + 256; if (n1 > N_NODES) n1 = N_NODES;
    int bstart = rowptr[n0], bend = rowptr[n1];
    for (int e = bstart + blockIdx.y * 256 + threadIdx.x; e < bend; e += 256 * 8) {
        unsigned p = ebin[e];
        int dst = n0 + (int)((p >> 20) & 255u);
        int pos = atomicAdd(&cursor[dst], 1);
        epack[pos] = p;                               // src:16 | attr:4
    }
}

// ------- fused Q/K/V/Skip GEMM; K,V emitted as packed bf16 -------
template <int DIN>
__global__ __launch_bounds__(256) void qkvs_kernel(
        const float* __restrict__ X,
        const float* __restrict__ Wq, const float* __restrict__ bq,
        const float* __restrict__ Wk, const float* __restrict__ bk,
        const float* __restrict__ Wv, const float* __restrict__ bv,
        const float* __restrict__ Ws, const float* __restrict__ bs,
        float* __restrict__ Q, unsigned* __restrict__ KVh,
        float* __restrict__ S) {
    __shared__ float xs[32][DIN];
    const int row0 = blockIdx.x * 32;
    const int tid = threadIdx.x;
    const int f4_per_row = DIN / 4;
    const int nf4 = 32 * f4_per_row;
    for (int i = tid; i < nf4; i += 256) {
        int row = row0 + i / f4_per_row;
        float4 v = make_float4(0.f, 0.f, 0.f, 0.f);
        if (row < N_NODES) v = ((const float4*)X)[(size_t)row0 * f4_per_row + i];
        ((float4*)&xs[0][0])[i] = v;
    }
    __syncthreads();
    const int c = tid & 63;        // output column
    const int w = tid >> 6;        // wave id: rows w, w+4, ..., w+28
    float aq[8], ak[8], av[8], as_[8];
    float bq_ = bq[c], bk_ = bk[c], bv_ = bv[c], bs_ = bs[c];
    #pragma unroll
    for (int j = 0; j < 8; ++j) { aq[j] = bq_; ak[j] = bk_; av[j] = bv_; as_[j] = bs_; }
    for (int k0 = 0; k0 < DIN; k0 += 4) {
        float4 xv4[8];
        #pragma unroll
        for (int j = 0; j < 8; ++j)
            xv4[j] = *(const float4*)&xs[w + j * 4][k0];   // broadcast b128 reads
        #pragma unroll
        for (int kk = 0; kk < 4; ++kk) {
            int k = k0 + kk;
            float wq = Wq[k * 64 + c], wk = Wk[k * 64 + c];
            float wv = Wv[k * 64 + c], ws = Ws[k * 64 + c];
            #pragma unroll
            for (int j = 0; j < 8; ++j) {
                float xv = (kk == 0) ? xv4[j].x : (kk == 1) ? xv4[j].y
                         : (kk == 2) ? xv4[j].z : xv4[j].w;
                aq[j]  = fmaf(xv, wq, aq[j]);
                ak[j]  = fmaf(xv, wk, ak[j]);
                av[j]  = fmaf(xv, wv, av[j]);
                as_[j] = fmaf(xv, ws, as_[j]);
            }
        }
    }
    #pragma unroll
    for (int j = 0; j < 8; ++j) {
        int row = row0 + w + j * 4;             // uniform across wave
        if (row < N_NODES) {
            Q[row * 64 + c] = aq[j];
            S[row * 64 + c] = as_[j];
            float kn = __shfl_down(ak[j], 1);
            float vn = __shfl_down(av[j], 1);
            if (!(c & 1)) {
                KVh[row * 64 + (c >> 1)]      = bf16pack(ak[j], kn);
                KVh[row * 64 + 32 + (c >> 1)] = bf16pack(av[j], vn);
            }
        }
    }
}

// ------- per-node attention: 8 edges/wave, bf16 K/V, te fully factored out -------
// out = [ Σ_e ea*v_src + Σ_a sden[a]*te_a ] / (Σ_a sden[a] + EPS) + S
__global__ __launch_bounds__(256) void conv_node_kernel(
        const int* __restrict__ rowptr, const unsigned* __restrict__ epack,
        const unsigned* __restrict__ KVh, const float* __restrict__ Qf,
        const float* __restrict__ S, const float* __restrict__ te,
        float* __restrict__ Hout) {
    __shared__ float4 tes4[V_SIZE * 16];    // te rows as float4: [a*16 + ch/4]
    __shared__ float qte_s[4][16];
    __shared__ float sden[4][16];
    for (int i = threadIdx.x; i < V_SIZE * 16; i += 256)
        tes4[i] = ((const float4*)te)[i];
    if (threadIdx.x < 64) sden[threadIdx.x >> 4][threadIdx.x & 15] = 0.f;
    __syncthreads();
    const int wv = threadIdx.x >> 6;
    const int node = blockIdx.x * 4 + wv;    // N_NODES % 4 == 0, no tail
    const int lane = threadIdx.x & 63;
    const int g  = lane >> 3;      // edge slot (8 concurrent edges)
    const int lo = lane & 7;       // channel octet: ch = lo*8 .. lo*8+7
    const int e0 = rowptr[node], e1 = rowptr[node + 1];
    float4 qa = ((const float4*)Qf)[node * 16 + lo * 2];
    float4 qb = ((const float4*)Qf)[node * 16 + lo * 2 + 1];
    // prologue: group g computes qte for attrs 2g, 2g+1 (no redundancy)
    #pragma unroll
    for (int i = 0; i < 2; ++i) {
        int a = 2 * g + i;
        float4 ta = tes4[a * 16 + lo * 2];
        float4 tb = tes4[a * 16 + lo * 2 + 1];
        float t = qa.x * ta.x + qa.y * ta.y + qa.z * ta.z + qa.w * ta.w
                + qb.x * tb.x + qb.y * tb.y + qb.z * tb.z + qb.w * tb.w;
        t += __shfl_xor(t, 1); t += __shfl_xor(t, 2); t += __shfl_xor(t, 4);
        if (lo == 0) qte_s[wv][a] = t * 0.125f;
    }
    float acc[8] = {0.f, 0.f, 0.f, 0.f, 0.f, 0.f, 0.f, 0.f};
    const uint4* KV4 = (const uint4*)KVh;   // node row = 16 uint4 (8 K + 8 V)
    // prefetch epack one iteration ahead
    int e = e0 + g;
    bool v_cur = e < e1;
    unsigned p_cur = v_cur ? epack[e] : 0u;
    for (int eb = e0; eb < e1; eb += 8) {
        unsigned p = p_cur;
        bool valid = v_cur;
        int en = eb + 8 + g;
        v_cur = en < e1;
        p_cur = v_cur ? epack[en] : 0u;
        int src = p & 0xFFFF;
        int a = (p >> 16) & 15;
        uint4 kw = KV4[src * 16 + lo];
        uint4 vw = KV4[src * 16 + 8 + lo];
        float t = qa.x * bl(kw.x) + qa.y * bh(kw.x)
                + qa.z * bl(kw.y) + qa.w * bh(kw.y)
                + qb.x * bl(kw.z) + qb.y * bh(kw.z)
                + qb.z * bl(kw.w) + qb.w * bh(kw.w);
        t += __shfl_xor(t, 1); t += __shfl_xor(t, 2); t += __shfl_xor(t, 4);
        float ea = valid ? __expf(fmaf(t, 0.125f, qte_s[wv][a])) : 0.f;
        if (lo == 0 && valid) atomicAdd(&sden[wv][a], ea);
        acc[0] = fmaf(ea, bl(vw.x), acc[0]);
        acc[1] = fmaf(ea, bh(vw.x), acc[1]);
        acc[2] = fmaf(ea, bl(vw.y), acc[2]);
        acc[3] = fmaf(ea, bh(vw.y), acc[3]);
        acc[4] = fmaf(ea, bl(vw.z), acc[4]);
        acc[5] = fmaf(ea, bh(vw.z), acc[5]);
        acc[6] = fmaf(ea, bl(vw.w), acc[6]);
        acc[7] = fmaf(ea, bh(vw.w), acc[7]);
    }
    // per-attr epilogue: group g folds attrs 2g, 2g+1 into its partials
    float den = 0.f;
    #pragma unroll
    for (int i = 0; i < 2; ++i) {
        int a = 2 * g + i;
        float f = sden[wv][a];
        den += f;
        float4 ta = tes4[a * 16 + lo * 2];
        float4 tb = tes4[a * 16 + lo * 2 + 1];
        acc[0] = fmaf(f, ta.x, acc[0]);
        acc[1] = fmaf(f, ta.y, acc[1]);
        acc[2] = fmaf(f, ta.z, acc[2]);
        acc[3] = fmaf(f, ta.w, acc[3]);
        acc[4] = fmaf(f, tb.x, acc[4]);
        acc[5] = fmaf(f, tb.y, acc[5]);
        acc[6] = fmaf(f, tb.z, acc[6]);
        acc[7] = fmaf(f, tb.w, acc[7]);
    }
    // reduce across the 8 edge-slot groups (den per-group values are uniform
    // within a group, distinct across groups -> butterfly sums each group once)
    #pragma unroll
    for (int off = 8; off < 64; off <<= 1) {
        #pragma unroll
        for (int i = 0; i < 8; ++i) acc[i] += __shfl_xor(acc[i], off);
        den += __shfl_xor(den, off);
    }
    if (g == 0) {
        float inv = 1.f / (den + EPS_F);
        float4 sa = ((const float4*)S)[node * 16 + lo * 2];
        float4 sb = ((const float4*)S)[node * 16 + lo * 2 + 1];
        float4 oa, ob;
        oa.x = fmaxf(fmaf(acc[0], inv, sa.x), 0.f);
        oa.y = fmaxf(fmaf(acc[1], inv, sa.y), 0.f);
        oa.z = fmaxf(fmaf(acc[2], inv, sa.z), 0.f);
        oa.w = fmaxf(fmaf(acc[3], inv, sa.w), 0.f);
        ob.x = fmaxf(fmaf(acc[4], inv, sb.x), 0.f);
        ob.y = fmaxf(fmaf(acc[5], inv, sb.y), 0.f);
        ob.z = fmaxf(fmaf(acc[6], inv, sb.z), 0.f);
        ob.w = fmaxf(fmaf(acc[7], inv, sb.w), 0.f);
        ((float4*)Hout)[node * 16 + lo * 2] = oa;
        ((float4*)Hout)[node * 16 + lo * 2 + 1] = ob;
    }
}

// ---------------- final projection: 16 lanes per node, coalesced ----------------
__global__ void out_kernel(const float* __restrict__ Hf,
                           const float* __restrict__ Wout,
                           const float* __restrict__ bout,
                           float* __restrict__ out) {
    int node = blockIdx.x * 16 + (threadIdx.x >> 4);
    if (node >= N_NODES) return;
    int lq = threadIdx.x & 15;
    float4 h = ((const float4*)Hf)[node * 16 + lq];
    int k0 = lq * 4;
    float p0 = h.x * Wout[(k0 + 0) * 2] + h.y * Wout[(k0 + 1) * 2]
             + h.z * Wout[(k0 + 2) * 2] + h.w * Wout[(k0 + 3) * 2];
    float p1 = h.x * Wout[(k0 + 0) * 2 + 1] + h.y * Wout[(k0 + 1) * 2 + 1]
             + h.z * Wout[(k0 + 2) * 2 + 1] + h.w * Wout[(k0 + 3) * 2 + 1];
    #pragma unroll
    for (int off = 1; off < 16; off <<= 1) {
        p0 += __shfl_xor(p0, off);
        p1 += __shfl_xor(p1, off);
    }
    if (lq == 0) {
        out[node * 2 + 0] = p0 + bout[0];
        out[node * 2 + 1] = p1 + bout[1];
    }
}

extern "C" void kernel_launch(void* const* d_in, const int* in_sizes, int n_in,
                              void* d_out, int out_size, void* d_ws, size_t ws_size,
                              hipStream_t stream) {
    const float* x        = (const float*)d_in[0];
    const int*   ei       = (const int*)  d_in[1];   // [2,E]: src row then dst row
    const int*   attr     = (const int*)  d_in[2];
    const float* edge_emb = (const float*)d_in[3];

    const float* c1_Wq = (const float*)d_in[4];  const float* c1_bq = (const float*)d_in[5];
    const float* c1_Wk = (const float*)d_in[6];  const float* c1_bk = (const float*)d_in[7];
    const float* c1_Wv = (const float*)d_in[8];  const float* c1_bv = (const float*)d_in[9];
    const float* c1_We = (const float*)d_in[10];
    const float* c1_Ws = (const float*)d_in[11]; const float* c1_bs = (const float*)d_in[12];

    const float* c2_Wq = (const float*)d_in[13]; const float* c2_bq = (const float*)d_in[14];
    const float* c2_Wk = (const float*)d_in[15]; const float* c2_bk = (const float*)d_in[16];
    const float* c2_Wv = (const float*)d_in[17]; const float* c2_bv = (const float*)d_in[18];
    const float* c2_We = (const float*)d_in[19];
    const float* c2_Ws = (const float*)d_in[20]; const float* c2_bs = (const float*)d_in[21];

    const float* Wout = (const float*)d_in[22];
    const float* bout = (const float*)d_in[23];

    // -------- workspace carve-up --------
    float* w = (float*)d_ws;
    float* te1 = w;                         // 1024
    float* te2 = te1 + 1024;                // 1024
    float* Q   = te2 + 1024;                // N*64 f32
    float* S   = Q  + N_NODES * 64;         // N*64 f32
    float* H1  = S  + N_NODES * 64;         // N*64 f32 (conv out; ebin aliases pre-conv1)
    unsigned* KVh = (unsigned*)(H1 + N_NODES * 64);   // N*64 u32 (bf16 K|V)
    int* deg    = (int*)(KVh + N_NODES * 64);          // N
    int* loc    = deg + N_NODES;            // N
    int* bsum   = loc + N_NODES;            // NB_SCAN
    int* bpre   = bsum + NB_SCAN;           // NB_SCAN
    int* rowptr = bpre + NB_SCAN;           // N+1
    int* cursor = rowptr + N_NODES + 1;     // N
    int* bcur   = cursor + N_NODES;         // NBKT
    unsigned* epack = (unsigned*)(bcur + NBKT);       // E
    unsigned* ebin  = (unsigned*)H1;        // E, aliases H1 (dead until conv1 output)

    const int edge_blocks = (E_EDGES + 255) / 256;
    const int bin_blocks  = (E_EDGES + EPB - 1) / EPB;
    const int node_grp    = (N_NODES + 3) / 4;        // conv_node: 4 nodes/block
    const int gemm_blocks = (N_NODES + 31) / 32;      // qkvs: 32 rows/block

    // edge-type tables for both convs
    table_kernel<<<8, 256, 0, stream>>>(edge_emb, c1_We, c2_We, te1, te2);

    // -------- CSR build (two-pass binned counting sort by dst) --------
    zero_deg_kernel<<<NB_SCAN, 256, 0, stream>>>(deg);
    hist_kernel<<<edge_blocks, 256, 0, stream>>>(ei, deg);
    scan1_kernel<<<NB_SCAN, 256, 0, stream>>>(deg, loc, bsum);
    scan2_kernel<<<1, 256, 0, stream>>>(bsum, bpre);
    scan3_kernel<<<NB_SCAN, 256, 0, stream>>>(loc, bpre, rowptr, cursor, bcur);
    bin_kernel<<<bin_blocks, 256, 0, stream>>>(ei, attr, bcur, ebin);
    place_kernel<<<dim3(NBKT, 8), 256, 0, stream>>>(rowptr, ebin, cursor, epack);

    // -------- conv1 --------
    qkvs_kernel<F_IN><<<gemm_blocks, 256, 0, stream>>>(
        x, c1_Wq, c1_bq, c1_Wk, c1_bk, c1_Wv, c1_bv, c1_Ws, c1_bs, Q, KVh, S);
    conv_node_kernel<<<node_grp, 256, 0, stream>>>(rowptr, epack, KVh, Q, S, te1, H1);

    // -------- conv2 --------
    qkvs_kernel<H_DIM><<<gemm_blocks, 256, 0, stream>>>(
        H1, c2_Wq, c2_bq, c2_Wk, c2_bk, c2_Wv, c2_bv, c2_Ws, c2_bs, Q, KVh, S);
    conv_node_kernel<<<node_grp, 256, 0, stream>>>(rowptr, epack, KVh, Q, S, te2, H1);

    // -------- output projection --------
    out_kernel<<<(N_NODES + 15) / 16, 256, 0, stream>>>(H1, Wout, bout, (float*)d_out);
}

// Round 9
// 471.182 us; speedup vs baseline: 9.9763x; 9.9763x over previous
//
#include <hip/hip_runtime.h>
#include <math.h>

#define N_NODES 50000
#define E_EDGES 1600000
#define F_IN    128
#define H_DIM   64
#define V_SIZE  16
#define OUT_DIM 2
#define EPS_F   1e-16f

#define NB_SCAN 196   // ceil(50000/256)
#define NBKT    196   // coarse buckets (256 nodes each)
#define EPB     4096  // edges per bin_kernel block

// -------- bf16 helpers --------
__device__ __forceinline__ unsigned bf16r(float x) {
    unsigned u = __float_as_uint(x);
    return (u + 0x7FFFu + ((u >> 16) & 1u)) >> 16;       // RNE
}
__device__ __forceinline__ unsigned bf16pack(float lo, float hi) {
    return bf16r(lo) | (bf16r(hi) << 16);
}
__device__ __forceinline__ float bl(unsigned w) { return __uint_as_float(w << 16); }
__device__ __forceinline__ float bh(unsigned w) { return __uint_as_float(w & 0xFFFF0000u); }

// ---------------- te = edge_emb @ We  (two [16,64] tables) ----------------
__global__ void table_kernel(const float* __restrict__ edge_emb,
                             const float* __restrict__ We1,
                             const float* __restrict__ We2,
                             float* __restrict__ te1, float* __restrict__ te2) {
    int t = blockIdx.x * blockDim.x + threadIdx.x;   // 0..2047
    if (t >= 2 * V_SIZE * H_DIM) return;
    int which = t >> 10;
    int idx = t & 1023;
    int v = idx >> 6, h = idx & 63;
    const float* We = which ? We2 : We1;
    float* te = which ? te2 : te1;
    float acc = 0.f;
    for (int k = 0; k < H_DIM; ++k)
        acc += edge_emb[v * H_DIM + k] * We[k * H_DIM + h];
    te[idx] = acc;
}

// ---------------- CSR build: counting sort of edges by dst ----------------
__global__ void zero_deg_kernel(int* __restrict__ deg) {
    int i = blockIdx.x * blockDim.x + threadIdx.x;
    if (i < N_NODES) deg[i] = 0;
}

__global__ void hist_kernel(const int* __restrict__ ei, int* __restrict__ deg) {
    int e = blockIdx.x * blockDim.x + threadIdx.x;
    if (e >= E_EDGES) return;
    atomicAdd(&deg[ei[E_EDGES + e]], 1);
}

__global__ void scan1_kernel(const int* __restrict__ deg,
                             int* __restrict__ loc, int* __restrict__ bsum) {
    __shared__ int s[256];
    int i = blockIdx.x * 256 + threadIdx.x;
    int v = (i < N_NODES) ? deg[i] : 0;
    s[threadIdx.x] = v;
    __syncthreads();
    for (int off = 1; off < 256; off <<= 1) {
        int t = (threadIdx.x >= off) ? s[threadIdx.x - off] : 0;
        __syncthreads();
        s[threadIdx.x] += t;
        __syncthreads();
    }
    if (i < N_NODES) loc[i] = s[threadIdx.x] - v;   // exclusive
    if (threadIdx.x == 255) bsum[blockIdx.x] = s[255];
}

__global__ void scan2_kernel(const int* __restrict__ bsum, int* __restrict__ bpre) {
    __shared__ int s[256];
    int t = threadIdx.x;
    int v = (t < NB_SCAN) ? bsum[t] : 0;
    s[t] = v;
    __syncthreads();
    for (int off = 1; off < 256; off <<= 1) {
        int u = (t >= off) ? s[t - off] : 0;
        __syncthreads();
        s[t] += u;
        __syncthreads();
    }
    if (t < NB_SCAN) bpre[t] = s[t] - v;            // exclusive
}

__global__ void scan3_kernel(const int* __restrict__ loc, const int* __restrict__ bpre,
                             int* __restrict__ rowptr, int* __restrict__ cursor,
                             int* __restrict__ bcur) {
    int i = blockIdx.x * 256 + threadIdx.x;
    if (i < N_NODES) {
        int r = loc[i] + bpre[blockIdx.x];
        rowptr[i] = r;
        cursor[i] = r;
        if ((i & 255) == 0) bcur[i >> 8] = r;        // coarse-bucket base/cursor
    }
    if (i == 0) rowptr[N_NODES] = E_EDGES;
}

// -------- pass A: bin edges by dst>>8 --------
__global__ __launch_bounds__(256) void bin_kernel(const int* __restrict__ ei,
                                                  const int* __restrict__ attr,
                                                  int* __restrict__ bcur,
                                                  unsigned* __restrict__ ebin) {
    __shared__ unsigned skey[EPB];
    __shared__ unsigned char sbkt[EPB];
    __shared__ int hist[NBKT], base[NBKT];
    const int tid = threadIdx.x;
    for (int i = tid; i < NBKT; i += 256) hist[i] = 0;
    __syncthreads();
    const int e0 = blockIdx.x * EPB;
    for (int i = tid; i < EPB; i += 256) {
        int e = e0 + i;
        if (e < E_EDGES) {
            int src = ei[e], dst = ei[E_EDGES + e], a = attr[e];
            skey[i] = (unsigned)src | ((unsigned)a << 16) | ((unsigned)(dst & 255) << 20);
            int b = dst >> 8;
            sbkt[i] = (unsigned char)b;
            atomicAdd(&hist[b], 1);
        } else {
            sbkt[i] = 0xFF;
        }
    }
    __syncthreads();
    for (int i = tid; i < NBKT; i += 256) {
        int h = hist[i];
        base[i] = h ? atomicAdd(&bcur[i], h) : 0;
        hist[i] = 0;                                  // reuse as rank counter
    }
    __syncthreads();
    for (int i = tid; i < EPB; i += 256) {
        int b = sbkt[i];
        if (b != 0xFF) {
            int r = atomicAdd(&hist[b], 1);
            ebin[base[b] + r] = skey[i];
        }
    }
}

// -------- pass B: exact placement within 32KB bucket windows --------
__global__ __launch_bounds__(256) void place_kernel(const int* __restrict__ rowptr,
                                                    const unsigned* __restrict__ ebin,
                                                    int* __restrict__ cursor,
                                                    unsigned* __restrict__ epack) {
    int b = blockIdx.x;
    int n0 = b << 8;
    int n1 = n0 + 256; if (n1 > N_NODES) n1 = N_NODES;
    int bstart = rowptr[n0], bend = rowptr[n1];
    for (int e = bstart + blockIdx.y * 256 + threadIdx.x; e < bend; e += 256 * 8) {
        unsigned p = ebin[e];
        int dst = n0 + (int)((p >> 20) & 255u);
        int pos = atomicAdd(&cursor[dst], 1);
        epack[pos] = p;                               // src:16 | attr:4
    }
}

// ------- fused Q/K/V/Skip GEMM (round-7 body: scalar LDS reads, no spills);
//         K,V emitted as packed bf16 -------
template <int DIN>
__global__ __launch_bounds__(256) void qkvs_kernel(
        const float* __restrict__ X,
        const float* __restrict__ Wq, const float* __restrict__ bq,
        const float* __restrict__ Wk, const float* __restrict__ bk,
        const float* __restrict__ Wv, const float* __restrict__ bv,
        const float* __restrict__ Ws, const float* __restrict__ bs,
        float* __restrict__ Q, unsigned* __restrict__ KVh,
        float* __restrict__ S) {
    __shared__ float xs[32][DIN];
    const int row0 = blockIdx.x * 32;
    const int tid = threadIdx.x;
    const int f4_per_row = DIN / 4;
    const int nf4 = 32 * f4_per_row;
    for (int i = tid; i < nf4; i += 256) {
        int row = row0 + i / f4_per_row;
        float4 v = make_float4(0.f, 0.f, 0.f, 0.f);
        if (row < N_NODES) v = ((const float4*)X)[(size_t)row0 * f4_per_row + i];
        ((float4*)&xs[0][0])[i] = v;
    }
    __syncthreads();
    const int c = tid & 63;        // output column
    const int w = tid >> 6;        // wave id: rows w, w+4, ..., w+28
    float aq[8], ak[8], av[8], as_[8];
    float bq_ = bq[c], bk_ = bk[c], bv_ = bv[c], bs_ = bs[c];
    #pragma unroll
    for (int j = 0; j < 8; ++j) { aq[j] = bq_; ak[j] = bk_; av[j] = bv_; as_[j] = bs_; }
    #pragma unroll 2
    for (int k = 0; k < DIN; ++k) {
        float wq = Wq[k * 64 + c], wk = Wk[k * 64 + c];
        float wv = Wv[k * 64 + c], ws = Ws[k * 64 + c];
        #pragma unroll
        for (int j = 0; j < 8; ++j) {
            float xv = xs[w + j * 4][k];
            aq[j]  = fmaf(xv, wq, aq[j]);
            ak[j]  = fmaf(xv, wk, ak[j]);
            av[j]  = fmaf(xv, wv, av[j]);
            as_[j] = fmaf(xv, ws, as_[j]);
        }
    }
    #pragma unroll
    for (int j = 0; j < 8; ++j) {
        int row = row0 + w + j * 4;             // uniform across wave
        if (row < N_NODES) {
            Q[row * 64 + c] = aq[j];
            S[row * 64 + c] = as_[j];
            float kn = __shfl_down(ak[j], 1);
            float vn = __shfl_down(av[j], 1);
            if (!(c & 1)) {
                KVh[row * 64 + (c >> 1)]      = bf16pack(ak[j], kn);
                KVh[row * 64 + 32 + (c >> 1)] = bf16pack(av[j], vn);
            }
        }
    }
}

// ------- per-node attention: 8 edges/wave, bf16 K/V, te fully factored out -------
// out = [ Σ_e ea*v_src + Σ_a sden[a]*te_a ] / (Σ_a sden[a] + EPS) + S
__global__ __launch_bounds__(256) void conv_node_kernel(
        const int* __restrict__ rowptr, const unsigned* __restrict__ epack,
        const unsigned* __restrict__ KVh, const float* __restrict__ Qf,
        const float* __restrict__ S, const float* __restrict__ te,
        float* __restrict__ Hout) {
    __shared__ float4 tes4[V_SIZE * 16];    // te rows as float4: [a*16 + ch/4]
    __shared__ float qte_s[4][16];
    __shared__ float sden[4][16];
    for (int i = threadIdx.x; i < V_SIZE * 16; i += 256)
        tes4[i] = ((const float4*)te)[i];
    if (threadIdx.x < 64) sden[threadIdx.x >> 4][threadIdx.x & 15] = 0.f;
    __syncthreads();
    const int wv = threadIdx.x >> 6;
    const int node = blockIdx.x * 4 + wv;    // N_NODES % 4 == 0, no tail
    const int lane = threadIdx.x & 63;
    const int g  = lane >> 3;      // edge slot (8 concurrent edges)
    const int lo = lane & 7;       // channel octet: ch = lo*8 .. lo*8+7
    const int e0 = rowptr[node], e1 = rowptr[node + 1];
    float4 qa = ((const float4*)Qf)[node * 16 + lo * 2];
    float4 qb = ((const float4*)Qf)[node * 16 + lo * 2 + 1];
    // prologue: group g computes qte for attrs 2g, 2g+1 (no redundancy)
    #pragma unroll
    for (int i = 0; i < 2; ++i) {
        int a = 2 * g + i;
        float4 ta = tes4[a * 16 + lo * 2];
        float4 tb = tes4[a * 16 + lo * 2 + 1];
        float t = qa.x * ta.x + qa.y * ta.y + qa.z * ta.z + qa.w * ta.w
                + qb.x * tb.x + qb.y * tb.y + qb.z * tb.z + qb.w * tb.w;
        t += __shfl_xor(t, 1); t += __shfl_xor(t, 2); t += __shfl_xor(t, 4);
        if (lo == 0) qte_s[wv][a] = t * 0.125f;
    }
    float acc[8] = {0.f, 0.f, 0.f, 0.f, 0.f, 0.f, 0.f, 0.f};
    const uint4* KV4 = (const uint4*)KVh;   // node row = 16 uint4 (8 K + 8 V)
    // prefetch epack one iteration ahead
    int e = e0 + g;
    bool v_cur = e < e1;
    unsigned p_cur = v_cur ? epack[e] : 0u;
    for (int eb = e0; eb < e1; eb += 8) {
        unsigned p = p_cur;
        bool valid = v_cur;
        int en = eb + 8 + g;
        v_cur = en < e1;
        p_cur = v_cur ? epack[en] : 0u;
        int src = p & 0xFFFF;
        int a = (p >> 16) & 15;
        uint4 kw = KV4[src * 16 + lo];
        uint4 vw = KV4[src * 16 + 8 + lo];
        float t = qa.x * bl(kw.x) + qa.y * bh(kw.x)
                + qa.z * bl(kw.y) + qa.w * bh(kw.y)
                + qb.x * bl(kw.z) + qb.y * bh(kw.z)
                + qb.z * bl(kw.w) + qb.w * bh(kw.w);
        t += __shfl_xor(t, 1); t += __shfl_xor(t, 2); t += __shfl_xor(t, 4);
        float ea = valid ? __expf(fmaf(t, 0.125f, qte_s[wv][a])) : 0.f;
        if (lo == 0 && valid) atomicAdd(&sden[wv][a], ea);
        acc[0] = fmaf(ea, bl(vw.x), acc[0]);
        acc[1] = fmaf(ea, bh(vw.x), acc[1]);
        acc[2] = fmaf(ea, bl(vw.y), acc[2]);
        acc[3] = fmaf(ea, bh(vw.y), acc[3]);
        acc[4] = fmaf(ea, bl(vw.z), acc[4]);
        acc[5] = fmaf(ea, bh(vw.z), acc[5]);
        acc[6] = fmaf(ea, bl(vw.w), acc[6]);
        acc[7] = fmaf(ea, bh(vw.w), acc[7]);
    }
    // per-attr epilogue: group g folds attrs 2g, 2g+1 into its partials
    float den = 0.f;
    #pragma unroll
    for (int i = 0; i < 2; ++i) {
        int a = 2 * g + i;
        float f = sden[wv][a];
        den += f;
        float4 ta = tes4[a * 16 + lo * 2];
        float4 tb = tes4[a * 16 + lo * 2 + 1];
        acc[0] = fmaf(f, ta.x, acc[0]);
        acc[1] = fmaf(f, ta.y, acc[1]);
        acc[2] = fmaf(f, ta.z, acc[2]);
        acc[3] = fmaf(f, ta.w, acc[3]);
        acc[4] = fmaf(f, tb.x, acc[4]);
        acc[5] = fmaf(f, tb.y, acc[5]);
        acc[6] = fmaf(f, tb.z, acc[6]);
        acc[7] = fmaf(f, tb.w, acc[7]);
    }
    // reduce across the 8 edge-slot groups
    #pragma unroll
    for (int off = 8; off < 64; off <<= 1) {
        #pragma unroll
        for (int i = 0; i < 8; ++i) acc[i] += __shfl_xor(acc[i], off);
        den += __shfl_xor(den, off);
    }
    if (g == 0) {
        float inv = 1.f / (den + EPS_F);
        float4 sa = ((const float4*)S)[node * 16 + lo * 2];
        float4 sb = ((const float4*)S)[node * 16 + lo * 2 + 1];
        float4 oa, ob;
        oa.x = fmaxf(fmaf(acc[0], inv, sa.x), 0.f);
        oa.y = fmaxf(fmaf(acc[1], inv, sa.y), 0.f);
        oa.z = fmaxf(fmaf(acc[2], inv, sa.z), 0.f);
        oa.w = fmaxf(fmaf(acc[3], inv, sa.w), 0.f);
        ob.x = fmaxf(fmaf(acc[4], inv, sb.x), 0.f);
        ob.y = fmaxf(fmaf(acc[5], inv, sb.y), 0.f);
        ob.z = fmaxf(fmaf(acc[6], inv, sb.z), 0.f);
        ob.w = fmaxf(fmaf(acc[7], inv, sb.w), 0.f);
        ((float4*)Hout)[node * 16 + lo * 2] = oa;
        ((float4*)Hout)[node * 16 + lo * 2 + 1] = ob;
    }
}

// ---------------- final projection: 16 lanes per node, coalesced ----------------
__global__ void out_kernel(const float* __restrict__ Hf,
                           const float* __restrict__ Wout,
                           const float* __restrict__ bout,
                           float* __restrict__ out) {
    int node = blockIdx.x * 16 + (threadIdx.x >> 4);
    if (node >= N_NODES) return;
    int lq = threadIdx.x & 15;
    float4 h = ((const float4*)Hf)[node * 16 + lq];
    int k0 = lq * 4;
    float p0 = h.x * Wout[(k0 + 0) * 2] + h.y * Wout[(k0 + 1) * 2]
             + h.z * Wout[(k0 + 2) * 2] + h.w * Wout[(k0 + 3) * 2];
    float p1 = h.x * Wout[(k0 + 0) * 2 + 1] + h.y * Wout[(k0 + 1) * 2 + 1]
             + h.z * Wout[(k0 + 2) * 2 + 1] + h.w * Wout[(k0 + 3) * 2 + 1];
    #pragma unroll
    for (int off = 1; off < 16; off <<= 1) {
        p0 += __shfl_xor(p0, off);
        p1 += __shfl_xor(p1, off);
    }
    if (lq == 0) {
        out[node * 2 + 0] = p0 + bout[0];
        out[node * 2 + 1] = p1 + bout[1];
    }
}

extern "C" void kernel_launch(void* const* d_in, const int* in_sizes, int n_in,
                              void* d_out, int out_size, void* d_ws, size_t ws_size,
                              hipStream_t stream) {
    const float* x        = (const float*)d_in[0];
    const int*   ei       = (const int*)  d_in[1];   // [2,E]: src row then dst row
    const int*   attr     = (const int*)  d_in[2];
    const float* edge_emb = (const float*)d_in[3];

    const float* c1_Wq = (const float*)d_in[4];  const float* c1_bq = (const float*)d_in[5];
    const float* c1_Wk = (const float*)d_in[6];  const float* c1_bk = (const float*)d_in[7];
    const float* c1_Wv = (const float*)d_in[8];  const float* c1_bv = (const float*)d_in[9];
    const float* c1_We = (const float*)d_in[10];
    const float* c1_Ws = (const float*)d_in[11]; const float* c1_bs = (const float*)d_in[12];

    const float* c2_Wq = (const float*)d_in[13]; const float* c2_bq = (const float*)d_in[14];
    const float* c2_Wk = (const float*)d_in[15]; const float* c2_bk = (const float*)d_in[16];
    const float* c2_Wv = (const float*)d_in[17]; const float* c2_bv = (const float*)d_in[18];
    const float* c2_We = (const float*)d_in[19];
    const float* c2_Ws = (const float*)d_in[20]; const float* c2_bs = (const float*)d_in[21];

    const float* Wout = (const float*)d_in[22];
    const float* bout = (const float*)d_in[23];

    // -------- workspace carve-up --------
    float* w = (float*)d_ws;
    float* te1 = w;                         // 1024
    float* te2 = te1 + 1024;                // 1024
    float* Q   = te2 + 1024;                // N*64 f32
    float* S   = Q  + N_NODES * 64;         // N*64 f32
    float* H1  = S  + N_NODES * 64;         // N*64 f32 (conv out; ebin aliases pre-conv1)
    unsigned* KVh = (unsigned*)(H1 + N_NODES * 64);   // N*64 u32 (bf16 K|V)
    int* deg    = (int*)(KVh + N_NODES * 64);          // N
    int* loc    = deg + N_NODES;            // N
    int* bsum   = loc + N_NODES;            // NB_SCAN
    int* bpre   = bsum + NB_SCAN;           // NB_SCAN
    int* rowptr = bpre + NB_SCAN;           // N+1
    int* cursor = rowptr + N_NODES + 1;     // N
    int* bcur   = cursor + N_NODES;         // NBKT
    unsigned* epack = (unsigned*)(bcur + NBKT);       // E
    unsigned* ebin  = (unsigned*)H1;        // E, aliases H1 (dead until conv1 output)

    const int edge_blocks = (E_EDGES + 255) / 256;
    const int bin_blocks  = (E_EDGES + EPB - 1) / EPB;
    const int node_grp    = (N_NODES + 3) / 4;        // conv_node: 4 nodes/block
    const int gemm_blocks = (N_NODES + 31) / 32;      // qkvs: 32 rows/block

    // edge-type tables for both convs
    table_kernel<<<8, 256, 0, stream>>>(edge_emb, c1_We, c2_We, te1, te2);

    // -------- CSR build (two-pass binned counting sort by dst) --------
    zero_deg_kernel<<<NB_SCAN, 256, 0, stream>>>(deg);
    hist_kernel<<<edge_blocks, 256, 0, stream>>>(ei, deg);
    scan1_kernel<<<NB_SCAN, 256, 0, stream>>>(deg, loc, bsum);
    scan2_kernel<<<1, 256, 0, stream>>>(bsum, bpre);
    scan3_kernel<<<NB_SCAN, 256, 0, stream>>>(loc, bpre, rowptr, cursor, bcur);
    bin_kernel<<<bin_blocks, 256, 0, stream>>>(ei, attr, bcur, ebin);
    place_kernel<<<dim3(NBKT, 8), 256, 0, stream>>>(rowptr, ebin, cursor, epack);

    // -------- conv1 --------
    qkvs_kernel<F_IN><<<gemm_blocks, 256, 0, stream>>>(
        x, c1_Wq, c1_bq, c1_Wk, c1_bk, c1_Wv, c1_bv, c1_Ws, c1_bs, Q, KVh, S);
    conv_node_kernel<<<node_grp, 256, 0, stream>>>(rowptr, epack, KVh, Q, S, te1, H1);

    // -------- conv2 --------
    qkvs_kernel<H_DIM><<<gemm_blocks, 256, 0, stream>>>(
        H1, c2_Wq, c2_bq, c2_Wk, c2_bk, c2_Wv, c2_bv, c2_Ws, c2_bs, Q, KVh, S);
    conv_node_kernel<<<node_grp, 256, 0, stream>>>(rowptr, epack, KVh, Q, S, te2, H1);

    // -------- output projection --------
    out_kernel<<<(N_NODES + 15) / 16, 256, 0, stream>>>(H1, Wout, bout, (float*)d_out);
}

// Round 12
// 448.671 us; speedup vs baseline: 10.4768x; 1.0502x over previous
//
#include <hip/hip_runtime.h>
#include <math.h>

#define N_NODES 50000
#define E_EDGES 1600000
#define F_IN    128
#define H_DIM   64
#define V_SIZE  16
#define OUT_DIM 2
#define EPS_F   1e-16f

#define NB_SCAN 196   // ceil(50000/256)
#define NBKT    196   // coarse buckets (256 nodes each)
#define EPB     4096  // edges per bin_kernel block
#define BSTRIDE 9216  // fixed ebin bucket stride (mean 8192, sigma ~90 -> 11 sigma slack)

// -------- bf16 helpers --------
__device__ __forceinline__ unsigned bf16r(float x) {
    unsigned u = __float_as_uint(x);
    return (u + 0x7FFFu + ((u >> 16) & 1u)) >> 16;       // RNE
}
__device__ __forceinline__ unsigned bf16pack(float lo, float hi) {
    return bf16r(lo) | (bf16r(hi) << 16);
}
__device__ __forceinline__ float bl(unsigned w) { return __uint_as_float(w << 16); }
__device__ __forceinline__ float bh(unsigned w) { return __uint_as_float(w & 0xFFFF0000u); }

// ---------------- te = edge_emb @ We  (two [16,64] tables) ----------------
__global__ void table_kernel(const float* __restrict__ edge_emb,
                             const float* __restrict__ We1,
                             const float* __restrict__ We2,
                             float* __restrict__ te1, float* __restrict__ te2) {
    int t = blockIdx.x * blockDim.x + threadIdx.x;   // 0..2047
    if (t >= 2 * V_SIZE * H_DIM) return;
    int which = t >> 10;
    int idx = t & 1023;
    int v = idx >> 6, h = idx & 63;
    const float* We = which ? We2 : We1;
    float* te = which ? te2 : te1;
    float acc = 0.f;
    for (int k = 0; k < H_DIM; ++k)
        acc += edge_emb[v * H_DIM + k] * We[k * H_DIM + h];
    te[idx] = acc;
}

// ---------------- CSR build ----------------
__global__ void zero_kernel(int* __restrict__ deg, int* __restrict__ bfill) {
    int i = blockIdx.x * blockDim.x + threadIdx.x;
    if (i < N_NODES) deg[i] = 0;
    if (i < NBKT) bfill[i] = 0;
}

// pass A: bin edges by dst>>8 into fixed-stride buckets; also build per-node degree
__global__ __launch_bounds__(256) void bin_kernel(const int* __restrict__ ei,
                                                  const int* __restrict__ attr,
                                                  int* __restrict__ deg,
                                                  int* __restrict__ bfill,
                                                  unsigned* __restrict__ ebin) {
    __shared__ unsigned skey[EPB];
    __shared__ unsigned char sbkt[EPB];
    __shared__ int hist[NBKT], base[NBKT];
    const int tid = threadIdx.x;
    for (int i = tid; i < NBKT; i += 256) hist[i] = 0;
    __syncthreads();
    const int e0 = blockIdx.x * EPB;
    for (int i = tid; i < EPB; i += 256) {
        int e = e0 + i;
        if (e < E_EDGES) {
            int src = ei[e], dst = ei[E_EDGES + e], a = attr[e];
            skey[i] = (unsigned)src | ((unsigned)a << 16) | ((unsigned)(dst & 255) << 20);
            int b = dst >> 8;
            sbkt[i] = (unsigned char)b;
            atomicAdd(&hist[b], 1);
            atomicAdd(&deg[dst], 1);          // integrated per-node histogram
        } else {
            sbkt[i] = 0xFF;
        }
    }
    __syncthreads();
    for (int i = tid; i < NBKT; i += 256) {
        int h = hist[i];
        base[i] = h ? (i * BSTRIDE + atomicAdd(&bfill[i], h)) : 0;
        hist[i] = 0;                                  // reuse as rank counter
    }
    __syncthreads();
    for (int i = tid; i < EPB; i += 256) {
        int b = sbkt[i];
        if (b != 0xFF) {
            int r = atomicAdd(&hist[b], 1);
            ebin[base[b] + r] = skey[i];
        }
    }
}

__global__ void scan1_kernel(const int* __restrict__ deg,
                             int* __restrict__ loc, int* __restrict__ bsum) {
    __shared__ int s[256];
    int i = blockIdx.x * 256 + threadIdx.x;
    int v = (i < N_NODES) ? deg[i] : 0;
    s[threadIdx.x] = v;
    __syncthreads();
    for (int off = 1; off < 256; off <<= 1) {
        int t = (threadIdx.x >= off) ? s[threadIdx.x - off] : 0;
        __syncthreads();
        s[threadIdx.x] += t;
        __syncthreads();
    }
    if (i < N_NODES) loc[i] = s[threadIdx.x] - v;   // exclusive
    if (threadIdx.x == 255) bsum[blockIdx.x] = s[255];
}

__global__ void scan2_kernel(const int* __restrict__ bsum, int* __restrict__ bpre) {
    __shared__ int s[256];
    int t = threadIdx.x;
    int v = (t < NB_SCAN) ? bsum[t] : 0;
    s[t] = v;
    __syncthreads();
    for (int off = 1; off < 256; off <<= 1) {
        int u = (t >= off) ? s[t - off] : 0;
        __syncthreads();
        s[t] += u;
        __syncthreads();
    }
    if (t < NB_SCAN) bpre[t] = s[t] - v;            // exclusive
}

__global__ void scan3_kernel(const int* __restrict__ loc, const int* __restrict__ bpre,
                             int* __restrict__ rowptr, int* __restrict__ cursor) {
    int i = blockIdx.x * 256 + threadIdx.x;
    if (i < N_NODES) {
        int r = loc[i] + bpre[blockIdx.x];
        rowptr[i] = r;
        cursor[i] = r;
    }
    if (i == 0) rowptr[N_NODES] = E_EDGES;
}

// pass B: exact placement within 32KB bucket windows (L2-resident)
__global__ __launch_bounds__(256) void place_kernel(const int* __restrict__ bfill,
                                                    const unsigned* __restrict__ ebin,
                                                    int* __restrict__ cursor,
                                                    unsigned* __restrict__ epack) {
    int b = blockIdx.x;
    int n0 = b << 8;
    int cnt = bfill[b];
    for (int i = blockIdx.y * 256 + threadIdx.x; i < cnt; i += 256 * 8) {
        unsigned p = ebin[b * BSTRIDE + i];
        int dst = n0 + (int)((p >> 20) & 255u);
        int pos = atomicAdd(&cursor[dst], 1);
        epack[pos] = p;                               // src:16 | attr:4
    }
}

// ------- fused Q/K/V/Skip GEMM (scalar LDS reads, unroll 4 for W-load depth);
//         K,V emitted as packed bf16 -------
template <int DIN>
__global__ __launch_bounds__(256) void qkvs_kernel(
        const float* __restrict__ X,
        const float* __restrict__ Wq, const float* __restrict__ bq,
        const float* __restrict__ Wk, const float* __restrict__ bk,
        const float* __restrict__ Wv, const float* __restrict__ bv,
        const float* __restrict__ Ws, const float* __restrict__ bs,
        float* __restrict__ Q, unsigned* __restrict__ KVh,
        float* __restrict__ S) {
    __shared__ float xs[32][DIN];
    const int row0 = blockIdx.x * 32;
    const int tid = threadIdx.x;
    const int f4_per_row = DIN / 4;
    const int nf4 = 32 * f4_per_row;
    for (int i = tid; i < nf4; i += 256) {
        int row = row0 + i / f4_per_row;
        float4 v = make_float4(0.f, 0.f, 0.f, 0.f);
        if (row < N_NODES) v = ((const float4*)X)[(size_t)row0 * f4_per_row + i];
        ((float4*)&xs[0][0])[i] = v;
    }
    __syncthreads();
    const int c = tid & 63;        // output column
    const int w = tid >> 6;        // wave id: rows w, w+4, ..., w+28
    float aq[8], ak[8], av[8], as_[8];
    float bq_ = bq[c], bk_ = bk[c], bv_ = bv[c], bs_ = bs[c];
    #pragma unroll
    for (int j = 0; j < 8; ++j) { aq[j] = bq_; ak[j] = bk_; av[j] = bv_; as_[j] = bs_; }
    #pragma unroll 4
    for (int k = 0; k < DIN; ++k) {
        float wq = Wq[k * 64 + c], wk = Wk[k * 64 + c];
        float wv = Wv[k * 64 + c], ws = Ws[k * 64 + c];
        #pragma unroll
        for (int j = 0; j < 8; ++j) {
            float xv = xs[w + j * 4][k];
            aq[j]  = fmaf(xv, wq, aq[j]);
            ak[j]  = fmaf(xv, wk, ak[j]);
            av[j]  = fmaf(xv, wv, av[j]);
            as_[j] = fmaf(xv, ws, as_[j]);
        }
    }
    #pragma unroll
    for (int j = 0; j < 8; ++j) {
        int row = row0 + w + j * 4;             // uniform across wave
        if (row < N_NODES) {
            Q[row * 64 + c] = aq[j];
            S[row * 64 + c] = as_[j];
            float kn = __shfl_down(ak[j], 1);
            float vn = __shfl_down(av[j], 1);
            if (!(c & 1)) {
                KVh[row * 64 + (c >> 1)]      = bf16pack(ak[j], kn);
                KVh[row * 64 + 32 + (c >> 1)] = bf16pack(av[j], vn);
            }
        }
    }
}

// ------- per-node attention: 8 edges/wave, bf16 K/V, te fully factored out -------
// out = [ Σ_e ea*v_src + Σ_a sden[a]*te_a ] / (Σ_a sden[a] + EPS) + S
__global__ __launch_bounds__(256) void conv_node_kernel(
        const int* __restrict__ rowptr, const unsigned* __restrict__ epack,
        const unsigned* __restrict__ KVh, const float* __restrict__ Qf,
        const float* __restrict__ S, const float* __restrict__ te,
        float* __restrict__ Hout) {
    __shared__ float4 tes4[V_SIZE * 16];    // te rows as float4: [a*16 + ch/4]
    __shared__ float qte_s[4][16];
    __shared__ float sden[4][16];
    for (int i = threadIdx.x; i < V_SIZE * 16; i += 256)
        tes4[i] = ((const float4*)te)[i];
    if (threadIdx.x < 64) sden[threadIdx.x >> 4][threadIdx.x & 15] = 0.f;
    __syncthreads();
    const int wv = threadIdx.x >> 6;
    const int node = blockIdx.x * 4 + wv;    // N_NODES % 4 == 0, no tail
    const int lane = threadIdx.x & 63;
    const int g  = lane >> 3;      // edge slot (8 concurrent edges)
    const int lo = lane & 7;       // channel octet: ch = lo*8 .. lo*8+7
    const int e0 = rowptr[node], e1 = rowptr[node + 1];
    float4 qa = ((const float4*)Qf)[node * 16 + lo * 2];
    float4 qb = ((const float4*)Qf)[node * 16 + lo * 2 + 1];
    // prologue: group g computes qte for attrs 2g, 2g+1 (no redundancy)
    #pragma unroll
    for (int i = 0; i < 2; ++i) {
        int a = 2 * g + i;
        float4 ta = tes4[a * 16 + lo * 2];
        float4 tb = tes4[a * 16 + lo * 2 + 1];
        float t = qa.x * ta.x + qa.y * ta.y + qa.z * ta.z + qa.w * ta.w
                + qb.x * tb.x + qb.y * tb.y + qb.z * tb.z + qb.w * tb.w;
        t += __shfl_xor(t, 1); t += __shfl_xor(t, 2); t += __shfl_xor(t, 4);
        if (lo == 0) qte_s[wv][a] = t * 0.125f;
    }
    float acc[8] = {0.f, 0.f, 0.f, 0.f, 0.f, 0.f, 0.f, 0.f};
    const uint4* KV4 = (const uint4*)KVh;   // node row = 16 uint4 (8 K + 8 V)
    // prefetch epack one iteration ahead
    int e = e0 + g;
    bool v_cur = e < e1;
    unsigned p_cur = v_cur ? epack[e] : 0u;
    for (int eb = e0; eb < e1; eb += 8) {
        unsigned p = p_cur;
        bool valid = v_cur;
        int en = eb + 8 + g;
        v_cur = en < e1;
        p_cur = v_cur ? epack[en] : 0u;
        int src = p & 0xFFFF;
        int a = (p >> 16) & 15;
        uint4 kw = KV4[src * 16 + lo];
        uint4 vw = KV4[src * 16 + 8 + lo];
        float t = qa.x * bl(kw.x) + qa.y * bh(kw.x)
                + qa.z * bl(kw.y) + qa.w * bh(kw.y)
                + qb.x * bl(kw.z) + qb.y * bh(kw.z)
                + qb.z * bl(kw.w) + qb.w * bh(kw.w);
        t += __shfl_xor(t, 1); t += __shfl_xor(t, 2); t += __shfl_xor(t, 4);
        float ea = valid ? __expf(fmaf(t, 0.125f, qte_s[wv][a])) : 0.f;
        if (lo == 0 && valid) atomicAdd(&sden[wv][a], ea);
        acc[0] = fmaf(ea, bl(vw.x), acc[0]);
        acc[1] = fmaf(ea, bh(vw.x), acc[1]);
        acc[2] = fmaf(ea, bl(vw.y), acc[2]);
        acc[3] = fmaf(ea, bh(vw.y), acc[3]);
        acc[4] = fmaf(ea, bl(vw.z), acc[4]);
        acc[5] = fmaf(ea, bh(vw.z), acc[5]);
        acc[6] = fmaf(ea, bl(vw.w), acc[6]);
        acc[7] = fmaf(ea, bh(vw.w), acc[7]);
    }
    // per-attr epilogue: group g folds attrs 2g, 2g+1 into its partials
    float den = 0.f;
    #pragma unroll
    for (int i = 0; i < 2; ++i) {
        int a = 2 * g + i;
        float f = sden[wv][a];
        den += f;
        float4 ta = tes4[a * 16 + lo * 2];
        float4 tb = tes4[a * 16 + lo * 2 + 1];
        acc[0] = fmaf(f, ta.x, acc[0]);
        acc[1] = fmaf(f, ta.y, acc[1]);
        acc[2] = fmaf(f, ta.z, acc[2]);
        acc[3] = fmaf(f, ta.w, acc[3]);
        acc[4] = fmaf(f, tb.x, acc[4]);
        acc[5] = fmaf(f, tb.y, acc[5]);
        acc[6] = fmaf(f, tb.z, acc[6]);
        acc[7] = fmaf(f, tb.w, acc[7]);
    }
    // reduce across the 8 edge-slot groups
    #pragma unroll
    for (int off = 8; off < 64; off <<= 1) {
        #pragma unroll
        for (int i = 0; i < 8; ++i) acc[i] += __shfl_xor(acc[i], off);
        den += __shfl_xor(den, off);
    }
    if (g == 0) {
        float inv = 1.f / (den + EPS_F);
        float4 sa = ((const float4*)S)[node * 16 + lo * 2];
        float4 sb = ((const float4*)S)[node * 16 + lo * 2 + 1];
        float4 oa, ob;
        oa.x = fmaxf(fmaf(acc[0], inv, sa.x), 0.f);
        oa.y = fmaxf(fmaf(acc[1], inv, sa.y), 0.f);
        oa.z = fmaxf(fmaf(acc[2], inv, sa.z), 0.f);
        oa.w = fmaxf(fmaf(acc[3], inv, sa.w), 0.f);
        ob.x = fmaxf(fmaf(acc[4], inv, sb.x), 0.f);
        ob.y = fmaxf(fmaf(acc[5], inv, sb.y), 0.f);
        ob.z = fmaxf(fmaf(acc[6], inv, sb.z), 0.f);
        ob.w = fmaxf(fmaf(acc[7], inv, sb.w), 0.f);
        ((float4*)Hout)[node * 16 + lo * 2] = oa;
        ((float4*)Hout)[node * 16 + lo * 2 + 1] = ob;
    }
}

// ---------------- final projection: 16 lanes per node, coalesced ----------------
__global__ void out_kernel(const float* __restrict__ Hf,
                           const float* __restrict__ Wout,
                           const float* __restrict__ bout,
                           float* __restrict__ out) {
    int node = blockIdx.x * 16 + (threadIdx.x >> 4);
    if (node >= N_NODES) return;
    int lq = threadIdx.x & 15;
    float4 h = ((const float4*)Hf)[node * 16 + lq];
    int k0 = lq * 4;
    float p0 = h.x * Wout[(k0 + 0) * 2] + h.y * Wout[(k0 + 1) * 2]
             + h.z * Wout[(k0 + 2) * 2] + h.w * Wout[(k0 + 3) * 2];
    float p1 = h.x * Wout[(k0 + 0) * 2 + 1] + h.y * Wout[(k0 + 1) * 2 + 1]
             + h.z * Wout[(k0 + 2) * 2 + 1] + h.w * Wout[(k0 + 3) * 2 + 1];
    #pragma unroll
    for (int off = 1; off < 16; off <<= 1) {
        p0 += __shfl_xor(p0, off);
        p1 += __shfl_xor(p1, off);
    }
    if (lq == 0) {
        out[node * 2 + 0] = p0 + bout[0];
        out[node * 2 + 1] = p1 + bout[1];
    }
}

extern "C" void kernel_launch(void* const* d_in, const int* in_sizes, int n_in,
                              void* d_out, int out_size, void* d_ws, size_t ws_size,
                              hipStream_t stream) {
    const float* x        = (const float*)d_in[0];
    const int*   ei       = (const int*)  d_in[1];   // [2,E]: src row then dst row
    const int*   attr     = (const int*)  d_in[2];
    const float* edge_emb = (const float*)d_in[3];

    const float* c1_Wq = (const float*)d_in[4];  const float* c1_bq = (const float*)d_in[5];
    const float* c1_Wk = (const float*)d_in[6];  const float* c1_bk = (const float*)d_in[7];
    const float* c1_Wv = (const float*)d_in[8];  const float* c1_bv = (const float*)d_in[9];
    const float* c1_We = (const float*)d_in[10];
    const float* c1_Ws = (const float*)d_in[11]; const float* c1_bs = (const float*)d_in[12];

    const float* c2_Wq = (const float*)d_in[13]; const float* c2_bq = (const float*)d_in[14];
    const float* c2_Wk = (const float*)d_in[15]; const float* c2_bk = (const float*)d_in[16];
    const float* c2_Wv = (const float*)d_in[17]; const float* c2_bv = (const float*)d_in[18];
    const float* c2_We = (const float*)d_in[19];
    const float* c2_Ws = (const float*)d_in[20]; const float* c2_bs = (const float*)d_in[21];

    const float* Wout = (const float*)d_in[22];
    const float* bout = (const float*)d_in[23];

    // -------- workspace carve-up --------
    float* w = (float*)d_ws;
    float* te1 = w;                         // 1024
    float* te2 = te1 + 1024;                // 1024
    float* Q   = te2 + 1024;                // N*64 f32
    float* S   = Q  + N_NODES * 64;         // N*64 f32
    float* H1  = S  + N_NODES * 64;         // N*64 f32 (conv out; ebin aliases pre-conv1)
    unsigned* KVh = (unsigned*)(H1 + N_NODES * 64);   // N*64 u32 (bf16 K|V)
    int* deg    = (int*)(KVh + N_NODES * 64);          // N
    int* loc    = deg + N_NODES;            // N
    int* bsum   = loc + N_NODES;            // NB_SCAN
    int* bpre   = bsum + NB_SCAN;           // NB_SCAN
    int* rowptr = bpre + NB_SCAN;           // N+1
    int* cursor = rowptr + N_NODES + 1;     // N
    int* bfill  = cursor + N_NODES;         // NBKT
    unsigned* epack = (unsigned*)(bfill + NBKT);      // E
    unsigned* ebin  = (unsigned*)H1;        // NBKT*BSTRIDE (1.81M) <= N*64, aliases H1

    const int bin_blocks  = (E_EDGES + EPB - 1) / EPB;
    const int node_grp    = (N_NODES + 3) / 4;        // conv_node: 4 nodes/block
    const int gemm_blocks = (N_NODES + 31) / 32;      // qkvs: 32 rows/block

    // edge-type tables for both convs
    table_kernel<<<8, 256, 0, stream>>>(edge_emb, c1_We, c2_We, te1, te2);

    // -------- CSR build (binned counting sort; deg fused into bin pass) --------
    zero_kernel<<<NB_SCAN, 256, 0, stream>>>(deg, bfill);
    bin_kernel<<<bin_blocks, 256, 0, stream>>>(ei, attr, deg, bfill, ebin);
    scan1_kernel<<<NB_SCAN, 256, 0, stream>>>(deg, loc, bsum);
    scan2_kernel<<<1, 256, 0, stream>>>(bsum, bpre);
    scan3_kernel<<<NB_SCAN, 256, 0, stream>>>(loc, bpre, rowptr, cursor);
    place_kernel<<<dim3(NBKT, 8), 256, 0, stream>>>(bfill, ebin, cursor, epack);

    // -------- conv1 --------
    qkvs_kernel<F_IN><<<gemm_blocks, 256, 0, stream>>>(
        x, c1_Wq, c1_bq, c1_Wk, c1_bk, c1_Wv, c1_bv, c1_Ws, c1_bs, Q, KVh, S);
    conv_node_kernel<<<node_grp, 256, 0, stream>>>(rowptr, epack, KVh, Q, S, te1, H1);

    // -------- conv2 --------
    qkvs_kernel<H_DIM><<<gemm_blocks, 256, 0, stream>>>(
        H1, c2_Wq, c2_bq, c2_Wk, c2_bk, c2_Wv, c2_bv, c2_Ws, c2_bs, Q, KVh, S);
    conv_node_kernel<<<node_grp, 256, 0, stream>>>(rowptr, epack, KVh, Q, S, te2, H1);

    // -------- output projection --------
    out_kernel<<<(N_NODES + 15) / 16, 256, 0, stream>>>(H1, Wout, bout, (float*)d_out);
}